// Round 2
// baseline (109.207 us; speedup 1.0000x reference)
//
#include <hip/hip_runtime.h>

typedef short short8 __attribute__((ext_vector_type(8)));
typedef float floatx4 __attribute__((ext_vector_type(4)));
typedef unsigned int u32;

#define NEG_SLOPE 0.2f

// pack {bf16_rtne(b), bf16_rtne(a)} into one u32 (a in low half)
__device__ __forceinline__ u32 pk_rtne(float a, float b) {
    u32 ua = __float_as_uint(a); ua += 0x7fffu + ((ua >> 16) & 1u);
    u32 ub = __float_as_uint(b); ub += 0x7fffu + ((ub >> 16) & 1u);
    return __builtin_amdgcn_perm(ub, ua, 0x07060302);
}
// pack {trunc16(b), trunc16(a)} (v_perm grabs high halves; 1 inst per pair)
__device__ __forceinline__ u32 pk_trunc(float a, float b) {
    return __builtin_amdgcn_perm(__float_as_uint(b), __float_as_uint(a), 0x07060302);
}
// exact hi/lo split: hi = trunc16(x) (exact residual), lo = trunc16(x - hi_f).
// x = hi + lo + O(2^-16 x); dropped alo*blo term is O(2^-16) -> fp32-grade GEMM.
__device__ __forceinline__ void split_pk(float a, float b, u32& hi, u32& lo) {
    u32 ua = __float_as_uint(a), ub = __float_as_uint(b);
    hi = __builtin_amdgcn_perm(ub, ua, 0x07060302);
    float la = a - __uint_as_float(ua & 0xffff0000u);
    float lb = b - __uint_as_float(ub & 0xffff0000u);
    lo = __builtin_amdgcn_perm(__float_as_uint(lb), __float_as_uint(la), 0x07060302);
}
__device__ __forceinline__ void gl_lds16(const void* g, void* l) {
    __builtin_amdgcn_global_load_lds((__attribute__((address_space(1))) u32*)(void*)g,
                                     (__attribute__((address_space(3))) u32*)l, 16, 0, 0);
}

// Kernel 1: Wh = h @ W^T, split-bf16 (3 MFMA passes). 64x64 tile, one head per
// block, 1024 blocks (4/CU), 4 waves in 2x2. Outputs:
//  - WhF: Wh^T as pre-swizzled MFMA B-fragments [b4h][c32][nt][lane]{8 bf16}
//    with k-permutation: slot(q,jj) -> j = c32*32 + (jj<4 ? q*4+jj : 16+q*4+jj-4)
//    (lets each lane write its own acc quads; no cross-lane shuffle)
//  - E1F1[b4h,i] = (exp(s1), exp(0.2*s1)); E2F2[b4h,j] = m_j*(exp(s2), exp(0.2*s2))
__global__ __launch_bounds__(256, 4) void k_wh(
    const float* __restrict__ hin, const int* __restrict__ mask,
    const float* __restrict__ W, const float* __restrict__ a,
    unsigned short* __restrict__ WhF, float2* __restrict__ E1F1,
    float2* __restrict__ E2F2)
{
    __shared__ unsigned short Ahi[64 * 72], Alo[64 * 72];  // +8 pad: 4-bank rotate
    __shared__ unsigned short Bhi[64 * 72], Blo[64 * 72];
    __shared__ float2 sred[2][64];

    const int t = threadIdx.x;
    const int bi = blockIdx.x;
    const int mtile = bi >> 2, cb = bi & 3;     // cb = head (consecutive blocks share h tile)
    const int m0g = mtile * 64;
    const int b = m0g >> 10;
    const int i0 = m0g & 1023;
    const int b4h = b * 4 + cb;
    const int wid = t >> 6, lane = t & 63;
    const int wm = wid >> 1, wn = wid & 1;
    const int l15 = lane & 15, q = lane >> 4;

    floatx4 acc[2][2];
#pragma unroll
    for (int mt = 0; mt < 2; ++mt)
#pragma unroll
        for (int nt = 0; nt < 2; ++nt) {
            floatx4 z = {0.f, 0.f, 0.f, 0.f};
            acc[mt][nt] = z;
        }

    for (int kt = 0; kt < 4; ++kt) {
        const int k0 = kt * 64;
#pragma unroll
        for (int p = 0; p < 4; ++p) {
            int idx = t + 256 * p;
            int row = idx >> 4, c4 = idx & 15;
            float4 v = *(const float4*)&hin[((size_t)(m0g + row)) * 256 + k0 + c4 * 4];
            u32 h0, l0, h1, l1;
            split_pk(v.x, v.y, h0, l0);
            split_pk(v.z, v.w, h1, l1);
            *(uint2*)&Ahi[row * 72 + c4 * 4] = make_uint2(h0, h1);
            *(uint2*)&Alo[row * 72 + c4 * 4] = make_uint2(l0, l1);
        }
#pragma unroll
        for (int p = 0; p < 4; ++p) {
            int idx = t + 256 * p;
            int row = idx >> 4, c4 = idx & 15;
            float4 v = *(const float4*)&W[((size_t)(cb * 64 + row)) * 256 + k0 + c4 * 4];
            u32 h0, l0, h1, l1;
            split_pk(v.x, v.y, h0, l0);
            split_pk(v.z, v.w, h1, l1);
            *(uint2*)&Bhi[row * 72 + c4 * 4] = make_uint2(h0, h1);
            *(uint2*)&Blo[row * 72 + c4 * 4] = make_uint2(l0, l1);
        }
        __syncthreads();
#pragma unroll
        for (int ks = 0; ks < 2; ++ks) {
            short8 ah[2], al[2], bh[2], bl[2];
#pragma unroll
            for (int mt = 0; mt < 2; ++mt) {
                int r = wm * 32 + mt * 16 + l15;
                ah[mt] = *(const short8*)&Ahi[r * 72 + ks * 32 + q * 8];
                al[mt] = *(const short8*)&Alo[r * 72 + ks * 32 + q * 8];
            }
#pragma unroll
            for (int nt = 0; nt < 2; ++nt) {
                int r = wn * 32 + nt * 16 + l15;
                bh[nt] = *(const short8*)&Bhi[r * 72 + ks * 32 + q * 8];
                bl[nt] = *(const short8*)&Blo[r * 72 + ks * 32 + q * 8];
            }
#pragma unroll
            for (int mt = 0; mt < 2; ++mt)
#pragma unroll
                for (int nt = 0; nt < 2; ++nt) {
                    acc[mt][nt] = __builtin_amdgcn_mfma_f32_16x16x32_bf16(ah[mt], bh[nt], acc[mt][nt], 0, 0, 0);
                    acc[mt][nt] = __builtin_amdgcn_mfma_f32_16x16x32_bf16(ah[mt], bl[nt], acc[mt][nt], 0, 0, 0);
                    acc[mt][nt] = __builtin_amdgcn_mfma_f32_16x16x32_bf16(al[mt], bh[nt], acc[mt][nt], 0, 0, 0);
                }
        }
        __syncthreads();
    }

    // ---- epilogue ----
    // WhF fragments: lane(l15,q) holds rows q*4+r (mt=0) and 16+q*4+r (mt=1),
    // exactly the 8 j's of k-group q under our permutation. col = l15 = B's n.
    const int c32 = (i0 + wm * 32) >> 5;
#pragma unroll
    for (int nt = 0; nt < 2; ++nt) {
        int nt_a = wn * 2 + nt;
        uint4 v;
        v.x = pk_rtne(acc[0][nt][0], acc[0][nt][1]);
        v.y = pk_rtne(acc[0][nt][2], acc[0][nt][3]);
        v.z = pk_rtne(acc[1][nt][0], acc[1][nt][1]);
        v.w = pk_rtne(acc[1][nt][2], acc[1][nt][3]);
        *(uint4*)&WhF[(size_t)(((b4h * 32 + c32) * 4 + nt_a) * 64 + lane) * 8] = v;
    }

    // s1/s2 partial dot over this wave's 32 d-cols; butterfly over l15; cross-wn via LDS
    float a1v[2], a2v[2];
#pragma unroll
    for (int nt = 0; nt < 2; ++nt) {
        int d = wn * 32 + nt * 16 + l15;
        a1v[nt] = a[d];
        a2v[nt] = a[64 + d];
    }
    float s1p[2][4], s2p[2][4];
#pragma unroll
    for (int mt = 0; mt < 2; ++mt)
#pragma unroll
        for (int r = 0; r < 4; ++r) {
            s1p[mt][r] = acc[mt][0][r] * a1v[0] + acc[mt][1][r] * a1v[1];
            s2p[mt][r] = acc[mt][0][r] * a2v[0] + acc[mt][1][r] * a2v[1];
        }
#pragma unroll
    for (int off = 1; off <= 8; off <<= 1)
#pragma unroll
        for (int mt = 0; mt < 2; ++mt)
#pragma unroll
            for (int r = 0; r < 4; ++r) {
                s1p[mt][r] += __shfl_xor(s1p[mt][r], off, 64);
                s2p[mt][r] += __shfl_xor(s2p[mt][r], off, 64);
            }
    if (l15 == 0) {
#pragma unroll
        for (int mt = 0; mt < 2; ++mt)
#pragma unroll
            for (int r = 0; r < 4; ++r)
                sred[wn][wm * 32 + mt * 16 + q * 4 + r] = make_float2(s1p[mt][r], s2p[mt][r]);
    }
    __syncthreads();
    if (t < 64) {
        float s1 = sred[0][t].x + sred[1][t].x;
        float s2 = sred[0][t].y + sred[1][t].y;
        int i = i0 + t;
        E1F1[(size_t)b4h * 1024 + i] = make_float2(__expf(s1), __expf(NEG_SLOPE * s1));
        int mj = mask[b * 1024 + i];
        E2F2[(size_t)b4h * 1024 + i] =
            make_float2(mj ? __expf(s2) : 0.f, mj ? __expf(NEG_SLOPE * s2) : 0.f);
    }
}

// Kernel 2: out[i,:] = (sum_j w_ij Wh[j,:]) / (sum_j w_ij),
// w_ij = max(E1_i*E2_j, F1_i*F2_j). 1024 blocks (b,h,64 rows), 4 waves x 16 rows.
// Wh tile staged via double-buffered global_load_lds from pre-swizzled WhF;
// P built in-register in A-fragment layout (truncated bf16; row-sum uses the
// SAME truncated values so the softmax stays self-consistent).
__global__ __launch_bounds__(256, 4) void k_attn(
    const int* __restrict__ mask,
    const unsigned short* __restrict__ WhF,
    const float2* __restrict__ E1F1, const float2* __restrict__ E2F2,
    float* __restrict__ out)
{
    __shared__ unsigned short sB[2][8192];   // 2 x 16 KB fragment tiles
    __shared__ float2 sEF[2][128];

    const int t = threadIdx.x;
    const int bi = blockIdx.x;
    const int ib = bi & 15, hh = (bi >> 4) & 3, b = bi >> 6;
    const int i0 = ib * 64;
    const int b4h = b * 4 + hh;
    const int wid = t >> 6, lane = t & 63;
    const int l15 = lane & 15, q = lane >> 4;
    const int iw = i0 + wid * 16;

    float2 e1 = E1F1[(size_t)b4h * 1024 + iw + l15];
    const float E1 = e1.x, F1 = e1.y;

    floatx4 acc[4];
#pragma unroll
    for (int nt = 0; nt < 4; ++nt) {
        floatx4 z = {0.f, 0.f, 0.f, 0.f};
        acc[nt] = z;
    }
    float rs = 0.f;

    const char* gbase = (const char*)WhF + (size_t)b4h * 131072;  // 32*4*64*16 B per b4h

    // prefetch jt=0
    {
        const char* gp = gbase;
#pragma unroll
        for (int i = 0; i < 4; ++i)
            gl_lds16(gp + wid * 4096 + i * 1024 + lane * 16,
                     (char*)&sB[0][0] + wid * 4096 + i * 1024);
        if (t < 128) sEF[0][t] = E2F2[(size_t)b4h * 1024 + t];
    }

    for (int jt = 0; jt < 8; ++jt) {
        const int buf = jt & 1;
        __syncthreads();   // drains this wave's global_load_lds (vmcnt) + lds stores
        if (jt < 7) {
            const char* gp = gbase + (size_t)(jt + 1) * 16384;
#pragma unroll
            for (int i = 0; i < 4; ++i)
                gl_lds16(gp + wid * 4096 + i * 1024 + lane * 16,
                         (char*)&sB[buf ^ 1][0] + wid * 4096 + i * 1024);
            if (t < 128) sEF[buf ^ 1][t] = E2F2[(size_t)b4h * 1024 + (jt + 1) * 128 + t];
        }
#pragma unroll
        for (int ks = 0; ks < 4; ++ks) {
            const float4 eA0 = *(const float4*)&sEF[buf][ks * 32 + q * 4];
            const float4 eA1 = *(const float4*)&sEF[buf][ks * 32 + q * 4 + 2];
            const float4 eB0 = *(const float4*)&sEF[buf][ks * 32 + 16 + q * 4];
            const float4 eB1 = *(const float4*)&sEF[buf][ks * 32 + 16 + q * 4 + 2];
            float w0 = fmaxf(E1 * eA0.x, F1 * eA0.y);
            float w1 = fmaxf(E1 * eA0.z, F1 * eA0.w);
            float w2 = fmaxf(E1 * eA1.x, F1 * eA1.y);
            float w3 = fmaxf(E1 * eA1.z, F1 * eA1.w);
            float w4 = fmaxf(E1 * eB0.x, F1 * eB0.y);
            float w5 = fmaxf(E1 * eB0.z, F1 * eB0.w);
            float w6 = fmaxf(E1 * eB1.x, F1 * eB1.y);
            float w7 = fmaxf(E1 * eB1.z, F1 * eB1.w);
            union { short8 s; u32 u[4]; } af;
            af.u[0] = pk_trunc(w0, w1);
            af.u[1] = pk_trunc(w2, w3);
            af.u[2] = pk_trunc(w4, w5);
            af.u[3] = pk_trunc(w6, w7);
#pragma unroll
            for (int uu = 0; uu < 4; ++uu)
                rs += __uint_as_float(af.u[uu] << 16) +
                      __uint_as_float(af.u[uu] & 0xffff0000u);
#pragma unroll
            for (int nt = 0; nt < 4; ++nt) {
                short8 bf = *(const short8*)&sB[buf][(ks * 4 + nt) * 512 + lane * 8];
                acc[nt] = __builtin_amdgcn_mfma_f32_16x16x32_bf16(af.s, bf, acc[nt], 0, 0, 0);
            }
        }
    }

    rs += __shfl_xor(rs, 16, 64);
    rs += __shfl_xor(rs, 32, 64);

#pragma unroll
    for (int r = 0; r < 4; ++r) {
        int i = iw + q * 4 + r;
        float l = __shfl(rs, q * 4 + r, 64);
        int mi = mask[b * 1024 + i];
        float inv = (mi && l > 0.f) ? 1.0f / l : 0.f;
#pragma unroll
        for (int nt = 0; nt < 4; ++nt)
            out[((size_t)(b * 1024 + i)) * 256 + hh * 64 + nt * 16 + l15] = acc[nt][r] * inv;
    }
}

extern "C" void kernel_launch(void* const* d_in, const int* in_sizes, int n_in,
                              void* d_out, int out_size, void* d_ws, size_t ws_size,
                              hipStream_t stream) {
    const float* h = (const float*)d_in[0];
    const int* mask = (const int*)d_in[1];
    const float* W = (const float*)d_in[2];
    const float* a = (const float*)d_in[3];
    float* out = (float*)d_out;

    // ws: WhF bf16 fragments [64 b4h][32 c32][4 nt][64 lane][8] = 8 MiB; then E1F1, E2F2
    unsigned short* WhF = (unsigned short*)d_ws;
    float2* E1F1 = (float2*)((char*)d_ws + (size_t)64 * 32 * 4 * 64 * 8 * 2);
    float2* E2F2 = E1F1 + 64 * 1024;

    hipLaunchKernelGGL(k_wh, dim3(1024), dim3(256), 0, stream, h, mask, W, a, WhF, E1F1, E2F2);
    hipLaunchKernelGGL(k_attn, dim3(1024), dim3(256), 0, stream, mask, WhF, E1F1, E2F2, out);
}

// Round 3
// 104.298 us; speedup vs baseline: 1.0471x; 1.0471x over previous
//
#include <hip/hip_runtime.h>

typedef short short8 __attribute__((ext_vector_type(8)));
typedef float floatx4 __attribute__((ext_vector_type(4)));
typedef float floatx16 __attribute__((ext_vector_type(16)));
typedef unsigned int u32;

#define NEG_SLOPE 0.2f

// pack {bf16_rtne(b), bf16_rtne(a)} into one u32 (a in low half)
__device__ __forceinline__ u32 pk_rtne(float a, float b) {
    u32 ua = __float_as_uint(a); ua += 0x7fffu + ((ua >> 16) & 1u);
    u32 ub = __float_as_uint(b); ub += 0x7fffu + ((ub >> 16) & 1u);
    return __builtin_amdgcn_perm(ub, ua, 0x07060302);
}
// pack {trunc16(b), trunc16(a)} — 1 inst per pair
__device__ __forceinline__ u32 pk_trunc(float a, float b) {
    return __builtin_amdgcn_perm(__float_as_uint(b), __float_as_uint(a), 0x07060302);
}
__device__ __forceinline__ void gl_lds16(const void* g, void* l) {
    __builtin_amdgcn_global_load_lds((__attribute__((address_space(1))) u32*)(void*)g,
                                     (__attribute__((address_space(3))) u32*)l, 16, 0, 0);
}

// ---------------------------------------------------------------------------
// Kernel 1: Wh = h @ W^T (single-pass bf16 MFMA, 16x16x32), barrier-free main
// loop. Scores s1/s2 computed EXACTLY in fp32 via s = h · (W^T a)  (v-GEMV
// folded into the W staging pass). Outputs:
//  - WhF: Wh^T as pre-swizzled 32x32x16 MFMA *B*-fragments
//    [b4h][jt16(64)][nt32(2)][lane(64)][8 bf16]
//    with k-slot permutation pi(g,jj) = (jj&3) + 4*g + 8*(jj>>2)
//    (chosen so k_wh's 16x16 C-quads store with plain uint2 writes)
//  - E1F1[b4h,i] = (exp(s1), exp(0.2*s1)); E2F2[b4h,j] = m_j*(exp(s2), exp(0.2*s2))
// Grid 1024 = 256 mtiles x 4 heads; h-tile sharers stride 256 -> same XCD.
// ---------------------------------------------------------------------------
__global__ __launch_bounds__(256, 4) void k_wh(
    const float* __restrict__ hin, const int* __restrict__ mask,
    const float* __restrict__ W, const float* __restrict__ a,
    unsigned short* __restrict__ WhF, float2* __restrict__ E1F1,
    float2* __restrict__ E2F2)
{
    __shared__ unsigned short sBF[8 * 4 * 64 * 8];  // W as 16x16x32 B-frags, 32 KB
    __shared__ float sV1[256], sV2[256];

    const int t = threadIdx.x;
    const int bi = blockIdx.x;
    const int mtile = bi & 255, hh = bi >> 8;
    const int m0g = mtile * 64;             // global row = b*1024 + i0
    const int b = m0g >> 10, i0 = m0g & 1023;
    const int b4h = b * 4 + hh;
    const int wid = t >> 6, lane = t & 63;
    const int l15 = lane & 15, q = lane >> 4;

    sV1[t] = 0.f;
    sV2[t] = 0.f;
    __syncthreads();

    // ---- stage W (this head) as B-frags + v1/v2 partial GEMV ----
    float vp1[8] = {0, 0, 0, 0, 0, 0, 0, 0};
    float vp2[8] = {0, 0, 0, 0, 0, 0, 0, 0};
    {
        const int c = t & 31;               // k-chunk of 8 floats
        const int rb = t >> 5;
#pragma unroll
        for (int i = 0; i < 8; ++i) {
            int row = i * 8 + rb;           // d within head
            const float* gp = &W[((size_t)(hh * 64 + row)) * 256 + c * 8];
            float4 w0 = *(const float4*)gp;
            float4 w1 = *(const float4*)(gp + 4);
            float a1r = a[row], a2r = a[64 + row];
            vp1[0] += a1r * w0.x; vp1[1] += a1r * w0.y; vp1[2] += a1r * w0.z; vp1[3] += a1r * w0.w;
            vp1[4] += a1r * w1.x; vp1[5] += a1r * w1.y; vp1[6] += a1r * w1.z; vp1[7] += a1r * w1.w;
            vp2[0] += a2r * w0.x; vp2[1] += a2r * w0.y; vp2[2] += a2r * w0.z; vp2[3] += a2r * w0.w;
            vp2[4] += a2r * w1.x; vp2[5] += a2r * w1.y; vp2[6] += a2r * w1.z; vp2[7] += a2r * w1.w;
            uint4 pv;
            pv.x = pk_rtne(w0.x, w0.y); pv.y = pk_rtne(w0.z, w0.w);
            pv.z = pk_rtne(w1.x, w1.y); pv.w = pk_rtne(w1.z, w1.w);
            int kt = c >> 2, qq = c & 3, nt = row >> 4, r15 = row & 15;
            int idx16 = (kt * 4 + nt) * 64 + qq * 16 + r15;
            *(uint4*)&sBF[(idx16 ^ kt) * 8] = pv;   // XOR swizzle: 32-way -> 4-way
        }
    }
#pragma unroll
    for (int j = 0; j < 8; ++j) {
        vp1[j] += __shfl_xor(vp1[j], 32, 64);
        vp2[j] += __shfl_xor(vp2[j], 32, 64);
    }
    if (lane < 32) {
        const int c = t & 31;
#pragma unroll
        for (int j = 0; j < 8; ++j) {
            atomicAdd(&sV1[c * 8 + j], vp1[j]);
            atomicAdd(&sV2[c * 8 + j], vp2[j]);
        }
    }
    __syncthreads();

    // ---- main loop: A-frags direct from global, no barriers ----
    floatx4 acc[4];
#pragma unroll
    for (int nt = 0; nt < 4; ++nt) {
        floatx4 z = {0.f, 0.f, 0.f, 0.f};
        acc[nt] = z;
    }
    float s1a = 0.f, s2a = 0.f;
    const float* hrow = &hin[((size_t)(m0g + wid * 16 + l15)) * 256 + q * 8];
#pragma unroll
    for (int kt = 0; kt < 8; ++kt) {
        float4 h0 = *(const float4*)(hrow + kt * 32);
        float4 h1 = *(const float4*)(hrow + kt * 32 + 4);
        float4 v1a = *(const float4*)&sV1[kt * 32 + q * 8];
        float4 v1b = *(const float4*)&sV1[kt * 32 + q * 8 + 4];
        float4 v2a = *(const float4*)&sV2[kt * 32 + q * 8];
        float4 v2b = *(const float4*)&sV2[kt * 32 + q * 8 + 4];
        s1a += h0.x * v1a.x + h0.y * v1a.y + h0.z * v1a.z + h0.w * v1a.w
             + h1.x * v1b.x + h1.y * v1b.y + h1.z * v1b.z + h1.w * v1b.w;
        s2a += h0.x * v2a.x + h0.y * v2a.y + h0.z * v2a.z + h0.w * v2a.w
             + h1.x * v2b.x + h1.y * v2b.y + h1.z * v2b.z + h1.w * v2b.w;
        union { short8 s; uint4 u; } af;
        af.u.x = pk_rtne(h0.x, h0.y); af.u.y = pk_rtne(h0.z, h0.w);
        af.u.z = pk_rtne(h1.x, h1.y); af.u.w = pk_rtne(h1.z, h1.w);
#pragma unroll
        for (int nt = 0; nt < 4; ++nt) {
            int idx16 = (kt * 4 + nt) * 64 + lane;
            short8 bf = *(const short8*)&sBF[(idx16 ^ kt) * 8];
            acc[nt] = __builtin_amdgcn_mfma_f32_16x16x32_bf16(af.s, bf, acc[nt], 0, 0, 0);
        }
    }

    // ---- epilogue: store WhF as 32x32x16 B-frags under pi ----
    // source C (16x16): lane(l15,q) holds rows q*4+r, col nt*16+l15.
    // row&15 = q*4+r -> (g = q&1, jj = 4*(q>>1)+r)  [pi identity: 4q = 4(q&1)+8(q>>1)]
    const int jt16 = (i0 >> 4) + wid;       // 16-j tile index within head
    const int g = q & 1, jb = (q >> 1) * 4;
#pragma unroll
    for (int nt = 0; nt < 4; ++nt) {
        int nt32 = nt >> 1;
        int l31 = (nt & 1) * 16 + l15;
        uint2 pv;
        pv.x = pk_rtne(acc[nt][0], acc[nt][1]);
        pv.y = pk_rtne(acc[nt][2], acc[nt][3]);
        size_t idx = ((((size_t)b4h * 64 + jt16) * 2 + nt32) * 64 + (g * 32 + l31)) * 8 + jb;
        *(uint2*)&WhF[idx] = pv;
    }

    // ---- scores: fold q (xor 16,32), write E/F ----
    s1a += __shfl_xor(s1a, 16, 64); s1a += __shfl_xor(s1a, 32, 64);
    s2a += __shfl_xor(s2a, 16, 64); s2a += __shfl_xor(s2a, 32, 64);
    if (lane < 16) {
        int i = i0 + wid * 16 + lane;
        E1F1[(size_t)b4h * 1024 + i] = make_float2(__expf(s1a), __expf(NEG_SLOPE * s1a));
        int mj = mask[b * 1024 + i];
        E2F2[(size_t)b4h * 1024 + i] =
            make_float2(mj ? __expf(s2a) : 0.f, mj ? __expf(NEG_SLOPE * s2a) : 0.f);
    }
}

// ---------------------------------------------------------------------------
// Kernel 2: out[i,:] = (sum_j w_ij Wh[j,:]) / (sum_j w_ij),
// w_ij = max(E1_i*E2_j, F1_i*F2_j). 32x32x16 MFMA (32-row waves -> halved LDS
// traffic); denominator via ones-column MFMA (accL), exactly consistent with
// the truncated-bf16 P fed to the numerator. 512 blocks = (b4h, 128 rows);
// sharers of b4h at stride 64 -> same XCD -> WhF slab L2-resident.
// ---------------------------------------------------------------------------
__global__ __launch_bounds__(256, 2) void k_attn(
    const int* __restrict__ mask,
    const unsigned short* __restrict__ WhF,
    const float2* __restrict__ E1F1, const float2* __restrict__ E2F2,
    float* __restrict__ out)
{
    __shared__ unsigned short sB[2][8192];   // [jtile(8)][nt(2)][lane][8], 16 KB/buf
    __shared__ float2 sEF[2][128];

    const int t = threadIdx.x;
    const int bi = blockIdx.x;
    const int b4h = bi & 63, ib = bi >> 6;
    const int b = b4h >> 2, hh = b4h & 3;
    const int i0 = ib * 128;
    const int wid = t >> 6, lane = t & 63;
    const int l31 = lane & 31, g = lane >> 5;
    const int iw = i0 + wid * 32;

    float2 e1 = E1F1[(size_t)b4h * 1024 + iw + l31];   // A-operand row m = l31
    const float E1 = e1.x, F1 = e1.y;

    floatx16 acc0, acc1, accL;
#pragma unroll
    for (int r = 0; r < 16; ++r) { acc0[r] = 0.f; acc1[r] = 0.f; accL[r] = 0.f; }
    const short ob = (short)0x3F80;          // bf16 1.0
    const short8 ones = {ob, ob, ob, ob, ob, ob, ob, ob};

    const char* gbase = (const char*)WhF + (size_t)b4h * 131072;

    // prefetch jt=0
    {
#pragma unroll
        for (int i = 0; i < 4; ++i)
            gl_lds16(gbase + wid * 4096 + i * 1024 + lane * 16,
                     (char*)&sB[0][0] + wid * 4096 + i * 1024);
        if (wid == 1)
            gl_lds16((const char*)&E2F2[(size_t)b4h * 1024] + lane * 16, (char*)&sEF[0][0]);
    }

    for (int jt = 0; jt < 8; ++jt) {
        const int buf = jt & 1;
        __syncthreads();
        if (jt < 7) {
            const char* gp = gbase + (size_t)(jt + 1) * 16384;
#pragma unroll
            for (int i = 0; i < 4; ++i)
                gl_lds16(gp + wid * 4096 + i * 1024 + lane * 16,
                         (char*)&sB[buf ^ 1][0] + wid * 4096 + i * 1024);
            if (wid == 1)
                gl_lds16((const char*)&E2F2[(size_t)b4h * 1024 + (jt + 1) * 128] + lane * 16,
                         (char*)&sEF[buf ^ 1][0]);
        }
#pragma unroll
        for (int tl = 0; tl < 8; ++tl) {
            // slots jj 0..7 <-> j = tl*16 + {4g+0..3, 8+4g+0..3}   (pi map)
            const float4 eA0 = *(const float4*)&sEF[buf][tl * 16 + g * 4];
            const float4 eA1 = *(const float4*)&sEF[buf][tl * 16 + g * 4 + 2];
            const float4 eB0 = *(const float4*)&sEF[buf][tl * 16 + 8 + g * 4];
            const float4 eB1 = *(const float4*)&sEF[buf][tl * 16 + 8 + g * 4 + 2];
            float w0 = fmaxf(E1 * eA0.x, F1 * eA0.y);
            float w1 = fmaxf(E1 * eA0.z, F1 * eA0.w);
            float w2 = fmaxf(E1 * eA1.x, F1 * eA1.y);
            float w3 = fmaxf(E1 * eA1.z, F1 * eA1.w);
            float w4 = fmaxf(E1 * eB0.x, F1 * eB0.y);
            float w5 = fmaxf(E1 * eB0.z, F1 * eB0.w);
            float w6 = fmaxf(E1 * eB1.x, F1 * eB1.y);
            float w7 = fmaxf(E1 * eB1.z, F1 * eB1.w);
            union { short8 s; u32 u[4]; } af;
            af.u[0] = pk_trunc(w0, w1);
            af.u[1] = pk_trunc(w2, w3);
            af.u[2] = pk_trunc(w4, w5);
            af.u[3] = pk_trunc(w6, w7);
            short8 bf0 = *(const short8*)&sB[buf][((tl * 2 + 0) * 64 + lane) * 8];
            short8 bf1 = *(const short8*)&sB[buf][((tl * 2 + 1) * 64 + lane) * 8];
            acc0 = __builtin_amdgcn_mfma_f32_32x32x16_bf16(af.s, bf0, acc0, 0, 0, 0);
            acc1 = __builtin_amdgcn_mfma_f32_32x32x16_bf16(af.s, bf1, acc1, 0, 0, 0);
            accL = __builtin_amdgcn_mfma_f32_32x32x16_bf16(af.s, ones, accL, 0, 0, 0);
        }
    }

    // epilogue: C/D 32x32 layout: col = l31, row = (r&3) + 8*(r>>2) + 4*g
#pragma unroll
    for (int r = 0; r < 16; ++r) {
        int row = (r & 3) + 8 * (r >> 2) + 4 * g;
        int i = iw + row;
        float l = accL[r];
        int mi = mask[b * 1024 + i];
        float inv = (mi && l > 0.f) ? 1.0f / l : 0.f;
        size_t o = ((size_t)(b * 1024 + i)) * 256 + hh * 64;
        out[o + l31] = acc0[r] * inv;
        out[o + 32 + l31] = acc1[r] * inv;
    }
}

extern "C" void kernel_launch(void* const* d_in, const int* in_sizes, int n_in,
                              void* d_out, int out_size, void* d_ws, size_t ws_size,
                              hipStream_t stream) {
    const float* h = (const float*)d_in[0];
    const int* mask = (const int*)d_in[1];
    const float* W = (const float*)d_in[2];
    const float* a = (const float*)d_in[3];
    float* out = (float*)d_out;

    // ws: WhF bf16 frags [64 b4h][64 jt16][2 nt][64 lane][8] = 8 MiB; then E1F1, E2F2
    unsigned short* WhF = (unsigned short*)d_ws;
    float2* E1F1 = (float2*)((char*)d_ws + (size_t)64 * 64 * 2 * 64 * 8 * 2);
    float2* E2F2 = E1F1 + 64 * 1024;

    hipLaunchKernelGGL(k_wh, dim3(1024), dim3(256), 0, stream, h, mask, W, a, WhF, E1F1, E2F2);
    hipLaunchKernelGGL(k_attn, dim3(512), dim3(256), 0, stream, mask, WhF, E1F1, E2F2, out);
}